// Round 1
// baseline (2596.007 us; speedup 1.0000x reference)
//
#include <hip/hip_runtime.h>
#include <math.h>

#define B_ 8
#define N_ 1024
#define M_ 20000
#define C_ 80
#define G_ 64
#define SLOTS 16   // N_/64

__device__ __forceinline__ float iou1(float ax, float ay, float az, float aw,
                                      float bx, float by, float bz, float bw) {
    // legacy +1 convention, matching bbox_overlaps(mode='iou')
    float lx = fmaxf(ax, bx), ly = fmaxf(ay, by);
    float rx = fminf(az, bz), ry = fminf(aw, bw);
    float w = fmaxf(rx - lx + 1.0f, 0.0f), h = fmaxf(ry - ly + 1.0f, 0.0f);
    float ov = w * h;
    float a1 = (az - ax + 1.0f) * (aw - ay + 1.0f);
    float a2 = (bz - bx + 1.0f) * (bw - by + 1.0f);
    return ov / (a1 + a2 - ov);
}

__global__ __launch_bounds__(64) void nms_loss_kernel(
    const int* __restrict__ pos_inds, const int* __restrict__ pos_gt,
    const float* __restrict__ gt_bboxes, const float* __restrict__ bbox_preds,
    const float* __restrict__ cls_scores, const int* __restrict__ gt_labels,
    float* __restrict__ out) {
    const int b = blockIdx.x;
    const int lane = threadIdx.x;

    __shared__ float s_gtiou[G_ * G_];   // 16 KiB
    __shared__ float s_box[N_ * 4];      // 16 KiB (popped-box broadcast source)
    __shared__ int s_gt[N_];             // 4 KiB

    // --- gt-gt IoU table: lane l holds gt box l; broadcast row box via shfl ---
    const float* gb = gt_bboxes + (size_t)(b * G_ + lane) * 4;
    float g0 = gb[0], g1 = gb[1], g2 = gb[2], g3 = gb[3];
    for (int r = 0; r < G_; ++r) {
        float rx0 = __shfl(g0, r), ry0 = __shfl(g1, r);
        float rx1 = __shfl(g2, r), ry1 = __shfl(g3, r);
        s_gtiou[r * G_ + lane] = iou1(rx0, ry0, rx1, ry1, g0, g1, g2, g3);
    }

    // --- per-lane elements: j = t*64 + lane ---
    float bx0[SLOTS], by0[SLOTS], bx1[SLOTS], by1[SLOTS], sc[SLOTS];
    int gti[SLOTS];
    for (int t = 0; t < SLOTS; ++t) {
        int j = t * 64 + lane;
        const float* bp = bbox_preds + (size_t)(b * N_ + j) * 4;
        bx0[t] = bp[0]; by0[t] = bp[1]; bx1[t] = bp[2]; by1[t] = bp[3];
        s_box[j * 4 + 0] = bx0[t]; s_box[j * 4 + 1] = by0[t];
        s_box[j * 4 + 2] = bx1[t]; s_box[j * 4 + 3] = by1[t];
        int g = pos_gt[b * N_ + j];
        gti[t] = g;
        s_gt[j] = g;
        int lab = gt_labels[b * G_ + g];
        int pi = pos_inds[b * N_ + j];
        sc[t] = cls_scores[(size_t)b * M_ * C_ + (size_t)pi * C_ + lab];
    }
    __syncthreads();

    unsigned alive = 0xFFFFu;  // bit t = element t*64+lane alive
    int my_seen = -1;          // lane l holds seen[l] (G_ == wave width)
    float tpull = 0.f, tpush = 0.f;
    int pcnt = 0, qcnt = 0;

    for (int step = 0; step < N_; ++step) {
        if (__ballot(alive != 0u) == 0ull) break;  // all dead: remaining steps are no-ops

        // --- argmax over alive scores; tie -> lowest index (matches jnp.argmax) ---
        float best = -INFINITY;
        int bidx = 0x7fffffff;
#pragma unroll
        for (int t = 0; t < SLOTS; ++t) {
            if ((alive >> t) & 1u) {
                if (sc[t] > best) { best = sc[t]; bidx = t * 64 + lane; }
            }
        }
#pragma unroll
        for (int off = 32; off; off >>= 1) {
            float ob = __shfl_xor(best, off);
            int oi = __shfl_xor(bidx, off);
            if (ob > best || (ob == best && oi < bidx)) { best = ob; bidx = oi; }
        }
        const int i = bidx;
        const float score_i = best;
        const int g = s_gt[i];
        const float ix0 = s_box[i * 4 + 0], iy0 = s_box[i * 4 + 1];
        const float ix1 = s_box[i * 4 + 2], iy1 = s_box[i * 4 + 3];

        // --- pull (uses seen-state BEFORE update) ---
        int prev = __shfl(my_seen, g);
        float pull = 0.f;
        if (prev >= 0) {
            float ovpi = iou1(s_box[prev * 4 + 0], s_box[prev * 4 + 1],
                              s_box[prev * 4 + 2], s_box[prev * 4 + 3],
                              ix0, iy0, ix1, iy1);
            pull = -logf(0.5f + fmaxf(ovpi, 1e-6f)) * score_i;
        } else {
            if (lane == g) my_seen = i;  // first sighting of this gt
        }

        // --- remove i, then compute remaining (reference order) ---
        if (lane == (i & 63)) alive &= ~(1u << (i >> 6));
        bool remaining = (__ballot(alive != 0u) != 0ull);

        // --- overlap row + push terms ---
        unsigned newdead = 0u;
        int cnt = 0;
        float tsum = 0.f;
#pragma unroll
        for (int t = 0; t < SLOTS; ++t) {
            if ((alive >> t) & 1u) {
                float ov = iou1(ix0, iy0, ix1, iy1, bx0[t], by0[t], bx1[t], by1[t]);
                if (ov > 0.5f) {
                    newdead |= (1u << t);
                    int gj = gti[t];
                    if (gj != g && ov > s_gtiou[g * G_ + gj]) {
                        cnt += 1;
                        tsum += -logf(1.0f - ov) * sc[t];
                    }
                }
            }
        }
#pragma unroll
        for (int off = 32; off; off >>= 1) {
            cnt += __shfl_xor(cnt, off);
            tsum += __shfl_xor(tsum, off);
        }
        float push = (cnt > 0) ? (tsum / (float)cnt) : 0.f;

        if (remaining) {  // add = any_alive & remaining
            tpull += pull;
            tpush += push;
            qcnt += cnt;
        }
        pcnt += (prev >= 0) ? 1 : 0;  // NOT gated on remaining (matches reference)
        alive &= ~newdead;
    }

    if (lane == 0) {
        float pushb = tpush / ((float)qcnt + 1e-6f);
        float pullb = tpull / ((float)pcnt + 1e-6f);
        atomicAdd(&out[0], pushb * 0.125f);  // mean over B=8, PUSH_W=1
        atomicAdd(&out[1], pullb * 0.125f);  // PULL_W=1
    }
}

extern "C" void kernel_launch(void* const* d_in, const int* in_sizes, int n_in,
                              void* d_out, int out_size, void* d_ws, size_t ws_size,
                              hipStream_t stream) {
    const int* pos_inds = (const int*)d_in[0];
    const int* pos_gt = (const int*)d_in[1];
    const float* gt_bboxes = (const float*)d_in[2];
    const float* bbox_preds = (const float*)d_in[3];
    const float* cls_scores = (const float*)d_in[4];
    const int* gt_labels = (const int*)d_in[5];
    float* out = (float*)d_out;

    hipMemsetAsync(out, 0, 2 * sizeof(float), stream);  // d_out re-poisoned 0xAA each call
    nms_loss_kernel<<<dim3(B_), dim3(64), 0, stream>>>(
        pos_inds, pos_gt, gt_bboxes, bbox_preds, cls_scores, gt_labels, out);
}

// Round 2
// 1207.047 us; speedup vs baseline: 2.1507x; 2.1507x over previous
//
#include <hip/hip_runtime.h>
#include <math.h>

#define B_ 8
#define N_ 1024
#define M_ 20000
#define C_ 80
#define G_ 64
#define SLOTS 16   // N_/64
typedef unsigned long long ull;

__device__ __forceinline__ float iou1(float ax, float ay, float az, float aw,
                                      float bx, float by, float bz, float bw) {
    // legacy +1 convention, exact reference arithmetic order
    float lx = fmaxf(ax, bx), ly = fmaxf(ay, by);
    float rx = fminf(az, bz), ry = fminf(aw, bw);
    float w = fmaxf(rx - lx + 1.0f, 0.0f), h = fmaxf(ry - ly + 1.0f, 0.0f);
    float ov = w * h;
    float a1 = (az - ax + 1.0f) * (aw - ay + 1.0f);
    float a2 = (bz - bx + 1.0f) * (bw - by + 1.0f);
    return ov / (a1 + a2 - ov);
}

__global__ __launch_bounds__(64) void nms_loss_kernel(
    const int* __restrict__ pos_inds, const int* __restrict__ pos_gt,
    const float* __restrict__ gt_bboxes, const float* __restrict__ bbox_preds,
    const float* __restrict__ cls_scores, const int* __restrict__ gt_labels,
    float* __restrict__ out) {
    const int b = blockIdx.x;
    const int lane = threadIdx.x;

    __shared__ float s_gtiou[G_ * G_];   // 16 KiB
    __shared__ ull   s_keys[N_];         //  8 KiB  (sort keys; low 32 = orig idx)
    __shared__ float s_elem[N_ * 8];     // 32 KiB  (sorted: x0,y0,x1,y1,g,score,area,pad)

    // --- gt-gt IoU table (lane l holds gt box l; broadcast row via shfl) ---
    const float* gb = gt_bboxes + (size_t)(b * G_ + lane) * 4;
    float g0 = gb[0], g1 = gb[1], g2 = gb[2], g3 = gb[3];
    for (int r = 0; r < G_; ++r) {
        float rx0 = __shfl(g0, r), ry0 = __shfl(g1, r);
        float rx1 = __shfl(g2, r), ry1 = __shfl(g3, r);
        s_gtiou[r * G_ + lane] = iou1(rx0, ry0, rx1, ry1, g0, g1, g2, g3);
    }

    // --- build sort keys: descending score, tie -> ascending original index ---
    for (int t = 0; t < SLOTS; ++t) {
        int j = t * 64 + lane;
        int g = pos_gt[b * N_ + j];
        int lab = gt_labels[b * G_ + g];
        int pi = pos_inds[b * N_ + j];
        float s = cls_scores[(size_t)b * (M_ * C_) + (size_t)pi * C_ + lab];
        // positive floats: bits monotone; ~bits -> ascending key == descending score
        s_keys[j] = ((ull)(~__float_as_uint(s)) << 32) | (unsigned)j;
    }
    __syncthreads();

    // --- bitonic sort (ascending keys), single wave, 1024 elements ---
    for (int k = 2; k <= N_; k <<= 1) {
        for (int jj = k >> 1; jj > 0; jj >>= 1) {
#pragma unroll
            for (int u = 0; u < SLOTS; ++u) {
                int idx = u * 64 + lane;
                if ((idx & jj) == 0) {
                    int partner = idx | jj;
                    ull a = s_keys[idx], c = s_keys[partner];
                    bool up = ((idx & k) == 0);
                    if ((a > c) == up) { s_keys[idx] = c; s_keys[partner] = a; }
                }
            }
            __syncthreads();
        }
    }

    // --- gather element data into sorted order; lane owns positions [lane*16, lane*16+16) ---
    float bx0[SLOTS], by0[SLOTS], bz1[SLOTS], bw1[SLOTS], a2[SLOTS], sc[SLOTS];
    int gti[SLOTS];
#pragma unroll
    for (int u = 0; u < SLOTS; ++u) {
        int p = lane * SLOTS + u;
        ull key = s_keys[p];
        int j = (int)(unsigned)(key & 0xFFFFFFFFull);
        float s = __uint_as_float(~(unsigned)(key >> 32));   // exact score recovery
        const float* bp = bbox_preds + (size_t)(b * N_ + j) * 4;
        float x0 = bp[0], y0 = bp[1], x1 = bp[2], y1 = bp[3];
        int g = pos_gt[b * N_ + j];
        float area = (x1 - x0 + 1.0f) * (y1 - y0 + 1.0f);
        bx0[u] = x0; by0[u] = y0; bz1[u] = x1 + 1.0f; bw1[u] = y1 + 1.0f;
        a2[u] = area; sc[u] = s; gti[u] = g;
        float* e = s_elem + p * 8;
        e[0] = x0; e[1] = y0; e[2] = x1; e[3] = y1;
        e[4] = __int_as_float(g); e[5] = s; e[6] = area; e[7] = 0.f;
    }
    __syncthreads();

    unsigned mask = 0xFFFFu;       // bit u = sorted position lane*16+u alive
    int seen_flag = 0;             // lane g: gt g has a first-seen box
    float sx0 = 0.f, sy0 = 0.f, sx1 = 0.f, sy1 = 0.f;  // lane g: that box
    float tpull = 0.f, tpush = 0.f;
    int pcnt = 0, qcnt = 0;

    while (true) {
        ull bal = __ballot(mask != 0u);
        if (bal == 0ull) break;
        // next pop = globally first alive sorted position (highest score, tie lowest idx)
        int l = __ffsll(bal) - 1;
        unsigned ml = (unsigned)__builtin_amdgcn_readlane((int)mask, l);
        int t = __ffs((int)ml) - 1;
        int p = l * SLOTS + t;

        const float* e = s_elem + p * 8;   // uniform broadcast reads (2x ds_read_b128)
        float ix0 = e[0], iy0 = e[1], ix1 = e[2], iy1 = e[3];
        int g = __float_as_int(e[4]);
        float score_i = e[5];
        float a1 = e[6];

        // --- pull (seen-state before update; wave-uniform branch) ---
        int hs = __builtin_amdgcn_readlane(seen_flag, g);
        float pull = 0.f;
        if (hs) {
            float px0 = __int_as_float(__builtin_amdgcn_readlane(__float_as_int(sx0), g));
            float py0 = __int_as_float(__builtin_amdgcn_readlane(__float_as_int(sy0), g));
            float px1 = __int_as_float(__builtin_amdgcn_readlane(__float_as_int(sx1), g));
            float py1 = __int_as_float(__builtin_amdgcn_readlane(__float_as_int(sy1), g));
            float ovpi = iou1(px0, py0, px1, py1, ix0, iy0, ix1, iy1);
            pull = -__logf(0.5f + fmaxf(ovpi, 1e-6f)) * score_i;
            pcnt += 1;                      // NOT gated on remaining (matches reference)
        } else if (lane == g) {
            seen_flag = 1; sx0 = ix0; sy0 = iy0; sx1 = ix1; sy1 = iy1;
        }

        // --- remove popped, then 'remaining' (reference order) ---
        if (lane == l) mask &= ~(1u << t);
        bool remaining = (__ballot(mask != 0u) != 0ull);
        if (!remaining) break;   // this step's pull/push not accumulated; later steps no-op

        // --- push / suppression: division-free kill test (iou>0.5 <=> 3I > a1+a2) ---
        float az1 = ix1 + 1.0f, aw1 = iy1 + 1.0f;
        unsigned kill = 0u; int cnt = 0; float tsum = 0.f;
#pragma unroll
        for (int u = 0; u < SLOTS; ++u) {
            float lx = fmaxf(ix0, bx0[u]);
            float ly = fmaxf(iy0, by0[u]);
            float rx = fminf(az1, bz1[u]);
            float ry = fminf(aw1, bw1[u]);
            float w = fmaxf(rx - lx, 0.0f);
            float h = fmaxf(ry - ly, 0.0f);
            float I = w * h;
            if (3.0f * I > a1 + a2[u]) {    // dead slots: bx0 poisoned -> I=0, never fires
                kill |= (1u << u);
                bx0[u] = 3e37f;             // poison: excluded from all future steps
                int gj = gti[u];
                if (gj != g) {              // popped element self-kills here, gj==g skips terms
                    float ov = I / (a1 + a2[u] - I);
                    if (ov > s_gtiou[g * G_ + gj]) { cnt += 1; tsum -= __logf(1.0f - ov) * sc[u]; }
                }
            }
        }
        mask &= ~kill;

        tpull += pull;
        if (__ballot(cnt != 0) != 0ull) {   // reduce only when a push term fired (rare)
            int ct = cnt; float ts = tsum;
#pragma unroll
            for (int off = 32; off; off >>= 1) {
                ct += __shfl_xor(ct, off);
                ts += __shfl_xor(ts, off);
            }
            tpush += ts / (float)ct;
            qcnt += ct;
        }
    }

    if (lane == 0) {
        atomicAdd(&out[0], (tpush / ((float)qcnt + 1e-6f)) * 0.125f);  // mean push, B=8
        atomicAdd(&out[1], (tpull / ((float)pcnt + 1e-6f)) * 0.125f);  // mean pull
    }
}

extern "C" void kernel_launch(void* const* d_in, const int* in_sizes, int n_in,
                              void* d_out, int out_size, void* d_ws, size_t ws_size,
                              hipStream_t stream) {
    const int* pos_inds = (const int*)d_in[0];
    const int* pos_gt = (const int*)d_in[1];
    const float* gt_bboxes = (const float*)d_in[2];
    const float* bbox_preds = (const float*)d_in[3];
    const float* cls_scores = (const float*)d_in[4];
    const int* gt_labels = (const int*)d_in[5];
    float* out = (float*)d_out;

    hipMemsetAsync(out, 0, 2 * sizeof(float), stream);  // d_out re-poisoned 0xAA each call
    nms_loss_kernel<<<dim3(B_), dim3(64), 0, stream>>>(
        pos_inds, pos_gt, gt_bboxes, bbox_preds, cls_scores, gt_labels, out);
}